// Round 4
// baseline (542.174 us; speedup 1.0000x reference)
//
#include <hip/hip_runtime.h>
#include <math.h>

typedef short bf8 __attribute__((ext_vector_type(8)));   // 8 bf16 = 4 VGPRs
typedef float f4 __attribute__((ext_vector_type(4)));

__device__ inline unsigned short f2bf(float f) {          // RNE f32 -> bf16
    unsigned int u = __float_as_uint(f);
    u = u + 0x7fffu + ((u >> 16) & 1u);
    return (unsigned short)(u >> 16);
}
__device__ inline float bf2f(unsigned short h) {
    return __uint_as_float(((unsigned int)h) << 16);
}
__device__ inline void split_bf(float v, unsigned short& h, unsigned short& l) {
    h = f2bf(v);
    l = f2bf(v - bf2f(h));
}
__device__ inline unsigned int packbf(unsigned short a, unsigned short b) {
    return (unsigned int)a | ((unsigned int)b << 16);
}
__device__ inline void async16(const void* g, void* l) {
    __builtin_amdgcn_global_load_lds(
        (const __attribute__((address_space(1))) unsigned int*)g,
        (__attribute__((address_space(3))) unsigned int*)l, 16, 0, 0);
}

// ---------- fuse row-mean + center + bf16 hi/lo split (K padded 784->800 with zeros) ----------
__global__ __launch_bounds__(256) void center_convert(const float* __restrict__ x,
        unsigned short* __restrict__ Xh, unsigned short* __restrict__ Xl) {
    int row = blockIdx.x;                       // b*512 + c
    const float* xr = x + (size_t)row * 784;
    int t = threadIdx.x;
    float4 vv = {0.f, 0.f, 0.f, 0.f};
    if (t < 196) vv = *(const float4*)(xr + t * 4);
    float s = vv.x + vv.y + vv.z + vv.w;
    #pragma unroll
    for (int o = 32; o > 0; o >>= 1) s += __shfl_down(s, o, 64);
    __shared__ float red[4];
    int lane = t & 63, wv = t >> 6;
    if (lane == 0) red[wv] = s;
    __syncthreads();
    float m = (red[0] + red[1] + red[2] + red[3]) * (1.0f / 784.0f);
    if (t < 200) {
        ushort4 hh = {0, 0, 0, 0}, ll = {0, 0, 0, 0};
        if (t < 196) {
            split_bf(vv.x - m, hh.x, ll.x);
            split_bf(vv.y - m, hh.y, ll.y);
            split_bf(vv.z - m, hh.z, ll.z);
            split_bf(vv.w - m, hh.w, ll.w);
        }
        *(ushort4*)&Xh[(size_t)row * 800 + t * 4] = hh;
        *(ushort4*)&Xl[(size_t)row * 800 + t * 4] = ll;
    }
}

// ---------- bf16x3 NT GEMM, 256x256 tile, BK=32, 512 thr (8 waves), dbuf counted-vmcnt ----------
// TRAFFIC-CUT version: staged panel bytes halve vs 128x128 (4+4 -> 2+2 MB per batch).
// grid 128 = 4 tiles x 32 batches (bz = bid&31 fastest => batch bz on XCD bz%8).
// LDS 128 KiB (2 x 64 KB buffers; epilogue overlays buffer region). 1 block/CU on 128 CUs.
// K-loop: single s_barrier per iter, depth-1 prefetch, counted s_waitcnt vmcnt(8).
// Wave grid 2x4: wave tile 128 rows x 64 cols, acc[8][4].
// MODE 0: C = A@B (S = M^2); ITER0: C *= invtr^2; CSUM=1 -> colsum
// MODE 1: C = 0.25(9*M*sc - 6*S + (A@B)*sc), sc = ITER0? invtr : 1; CSUM=2 -> vacc += vin.C
// MODE 3: C = (A@B)*cscale (cov); fused trace; CSUM=1 -> colsum(cov)
template<int MODE, int CSUM, int ITER0>
__global__ __launch_bounds__(512, 2) void gemm_full(
        const unsigned short* __restrict__ Ah, const unsigned short* __restrict__ Al,
        const unsigned short* __restrict__ Bh, const unsigned short* __restrict__ Bl,
        const unsigned short* __restrict__ Mh, const unsigned short* __restrict__ Ml,
        const unsigned short* __restrict__ Sh, const unsigned short* __restrict__ Sl,
        unsigned short* __restrict__ Ch, unsigned short* __restrict__ Cl,
        float* __restrict__ trp, float* __restrict__ csum, const float* __restrict__ vin,
        int K, int lda, float cscale) {
    // 2 staging bufs x 32768 shorts (Ah 8192 | Al 8192 | Bh 8192 | Bl 8192 shorts each 16KB)
    // epilogue overlay: slab tilef [64][257] f32 = 65792 B ; colred [16][256] f32 @ 66048
    __shared__ __align__(16) char smem[131072];
    unsigned short* stage = (unsigned short*)smem;
    float* tilef  = (float*)smem;
    float* colred = (float*)(smem + 66048);

    int bid = blockIdx.x;
    int bz = bid & 31;
    int tt = bid >> 5;                       // 0..3
    int by = tt >> 1, bx = tt & 1;           // 2x2 tiles of 256

    size_t sAB = (size_t)512 * lda;
    size_t sC  = (size_t)512 * 512;
    const unsigned short* pAh = Ah + (size_t)bz * sAB;
    const unsigned short* pAl = Al + (size_t)bz * sAB;
    const unsigned short* pBh = Bh + (size_t)bz * sAB;
    const unsigned short* pBl = Bl + (size_t)bz * sAB;

    int tid = threadIdx.x;
    int w = tid >> 6, l = tid & 63;
    int rb0 = by * 256, cb0 = bx * 256;

    // staging: wave w stages plane pl = w>>1 (0:Ah 1:Al 2:Bh 3:Bl), 8 units of 1KB each.
    // plane chunk = 256 rows x 32 k x 2B = 16KB = 1024 slots of 16B.
    // slot s: row r = s>>2, k-group g = (s&3)^((r>>1)&3)  (pre-swizzled global src,
    // linear LDS dest). unit u = (w&1)*8 + q, s = u*64 + l.
    int pl = w >> 1;
    const unsigned short* gp = (pl == 0) ? pAh : (pl == 1) ? pAl : (pl == 2) ? pBh : pBl;
    int rowbase = (pl < 2) ? rb0 : cb0;
    size_t goff[8];
    int ldsoff[8];
    #pragma unroll
    for (int q = 0; q < 8; ++q) {
        int u = (w & 1) * 8 + q;
        int s = u * 64 + l;
        int r = s >> 2, g = (s & 3) ^ ((r >> 1) & 3);
        goff[q] = (size_t)(rowbase + r) * lda + g * 8;
        ldsoff[q] = pl * 8192 + u * 512 + l * 8;     // shorts
    }

    f4 zero4 = {0.f, 0.f, 0.f, 0.f};
    f4 acc[8][4];
    #pragma unroll
    for (int i = 0; i < 8; ++i)
        #pragma unroll
        for (int j = 0; j < 4; ++j) acc[i][j] = zero4;

    int fr = l & 15, quad = l >> 4;
    int sw = quad ^ ((fr >> 1) & 3);
    int wr = w >> 2, wc = w & 3;             // wave tile: rows [wr*128,+128), cols [wc*64,+64)
    int NK = K >> 5;

    // prologue: stage chunk 0 into buf 0 (8 loads/wave in flight)
    #pragma unroll
    for (int q = 0; q < 8; ++q) async16(gp + goff[q], stage + ldsoff[q]);

    for (int ki = 0; ki < NK; ++ki) {
        __builtin_amdgcn_s_barrier();        // all waves done reading buf[(ki+1)&1] (prev iter)
        asm volatile("" ::: "memory");
        if (ki + 1 < NK) {                   // depth-1 prefetch into the just-freed buffer
            int k0 = (ki + 1) << 5;
            unsigned short* sb2 = stage + ((ki + 1) & 1) * 32768;
            #pragma unroll
            for (int q = 0; q < 8; ++q) async16(gp + goff[q] + k0, sb2 + ldsoff[q]);
            asm volatile("s_waitcnt vmcnt(8)" ::: "memory");   // buf[ki] landed; next 8 in flight
        } else {
            asm volatile("s_waitcnt vmcnt(0)" ::: "memory");
        }
        const unsigned short* sb = stage + (ki & 1) * 32768;
        bf8 bhf[4], blf[4];
        #pragma unroll
        for (int j = 0; j < 4; ++j) {
            int ob = ((wc * 64 + j * 16 + fr) * 4 + sw) * 8;
            bhf[j] = *(const bf8*)&sb[16384 + ob];
            blf[j] = *(const bf8*)&sb[24576 + ob];
        }
        __builtin_amdgcn_s_setprio(1);
        #pragma unroll
        for (int i = 0; i < 8; ++i) {
            int oa = ((wr * 128 + i * 16 + fr) * 4 + sw) * 8;
            bf8 ahf = *(const bf8*)&sb[oa];
            bf8 alf = *(const bf8*)&sb[8192 + oa];
            #pragma unroll
            for (int j = 0; j < 4; ++j) {
                acc[i][j] = __builtin_amdgcn_mfma_f32_16x16x32_bf16(ahf, bhf[j], acc[i][j], 0, 0, 0);
                acc[i][j] = __builtin_amdgcn_mfma_f32_16x16x32_bf16(ahf, blf[j], acc[i][j], 0, 0, 0);
                acc[i][j] = __builtin_amdgcn_mfma_f32_16x16x32_bf16(alf, bhf[j], acc[i][j], 0, 0, 0);
            }
        }
        __builtin_amdgcn_s_setprio(0);
    }
    __syncthreads();                          // full drain before LDS overlay

    float invtr_e = 1.0f;
    if ((MODE == 0 || MODE == 1) && ITER0) invtr_e = 1.0f / trp[bz];
    const float sc_g = (MODE == 3) ? cscale
                      : (MODE == 0 ? (ITER0 ? invtr_e * invtr_e : 1.0f)
                                   : (ITER0 ? invtr_e : 1.0f));

    unsigned short* qCh = Ch + (size_t)bz * sC;
    unsigned short* qCl = Cl + (size_t)bz * sC;
    const unsigned short* qMh = (MODE == 1) ? Mh + (size_t)bz * sC : nullptr;
    const unsigned short* qMl = (MODE == 1) ? Ml + (size_t)bz * sC : nullptr;
    const unsigned short* qSh = (MODE == 1) ? Sh + (size_t)bz * sC : nullptr;
    const unsigned short* qSl = (MODE == 1) ? Sl + (size_t)bz * sC : nullptr;

    int erow = tid >> 5;                     // 0..15
    int ec0  = (tid & 31) * 8;               // 0..248
    float cp[8] = {0.f, 0.f, 0.f, 0.f, 0.f, 0.f, 0.f, 0.f};

    // 4 slabs of 64 rows: acc -> f32 slab tile -> process/store
    #pragma unroll
    for (int s = 0; s < 4; ++s) {
        __syncthreads();
        if (wr == (s >> 1)) {
            int ibase = (s & 1) * 4;
            #pragma unroll
            for (int ii = 0; ii < 4; ++ii) {
                int rloc = ii * 16 + quad * 4;
                #pragma unroll
                for (int j = 0; j < 4; ++j) {
                    int cloc = wc * 64 + j * 16 + fr;
                    #pragma unroll
                    for (int r = 0; r < 4; ++r)
                        tilef[(rloc + r) * 257 + cloc] = acc[ibase + ii][j][r];
                }
            }
        }
        __syncthreads();
        #pragma unroll
        for (int p = 0; p < 4; ++p) {
            int row = erow + p * 16;                 // 0..63 within slab
            int grow = rb0 + s * 64 + row, gcol = cb0 + ec0;
            float vv[8];
            #pragma unroll
            for (int k = 0; k < 8; ++k) vv[k] = tilef[row * 257 + ec0 + k];
            size_t gaddr = (size_t)grow * 512 + gcol;
            if (MODE == 3 || MODE == 0) {
                #pragma unroll
                for (int k = 0; k < 8; ++k) vv[k] *= sc_g;
            }
            if (MODE == 1) {
                uint4 mh = *(const uint4*)&qMh[gaddr], ml = *(const uint4*)&qMl[gaddr];
                uint4 sh = *(const uint4*)&qSh[gaddr], sl = *(const uint4*)&qSl[gaddr];
                const unsigned int* mhp = (const unsigned int*)&mh; const unsigned int* mlp = (const unsigned int*)&ml;
                const unsigned int* shp = (const unsigned int*)&sh; const unsigned int* slp = (const unsigned int*)&sl;
                #pragma unroll
                for (int k = 0; k < 8; ++k) {
                    unsigned int hm = mhp[k >> 1], lm = mlp[k >> 1], hs = shp[k >> 1], ls = slp[k >> 1];
                    float mval = bf2f((unsigned short)((k & 1) ? (hm >> 16) : (hm & 0xffffu)))
                               + bf2f((unsigned short)((k & 1) ? (lm >> 16) : (lm & 0xffffu)));
                    float sval = bf2f((unsigned short)((k & 1) ? (hs >> 16) : (hs & 0xffffu)))
                               + bf2f((unsigned short)((k & 1) ? (ls >> 16) : (ls & 0xffffu)));
                    vv[k] = 0.25f * (9.0f * mval * sc_g - 6.0f * sval + vv[k] * sc_g);
                }
            }
            unsigned short h[8], lo[8];
            #pragma unroll
            for (int k = 0; k < 8; ++k) split_bf(vv[k], h[k], lo[k]);
            uint4 uh, ul;
            uh.x = packbf(h[0], h[1]); uh.y = packbf(h[2], h[3]); uh.z = packbf(h[4], h[5]); uh.w = packbf(h[6], h[7]);
            ul.x = packbf(lo[0], lo[1]); ul.y = packbf(lo[2], lo[3]); ul.z = packbf(lo[4], lo[5]); ul.w = packbf(lo[6], lo[7]);
            *(uint4*)&qCh[gaddr] = uh;
            *(uint4*)&qCl[gaddr] = ul;
            if (MODE == 3 && by == bx) {             // trace (diag tiles)
                int d = s * 64 + row - ec0;
                if (d >= 0 && d < 8) atomicAdd(&trp[bz], vv[d]);
            }
            if (CSUM == 1) {
                #pragma unroll
                for (int k = 0; k < 8; ++k) cp[k] += vv[k];
            } else if (CSUM == 2) {
                float wgt = vin[bz * 512 + grow];
                #pragma unroll
                for (int k = 0; k < 8; ++k) cp[k] += wgt * vv[k];
            }
        }
    }
    if (CSUM) {     // 16 row-groups x 256 cols -> 1 atomic/col
        __syncthreads();
        #pragma unroll
        for (int k = 0; k < 8; ++k) colred[erow * 256 + ec0 + k] = cp[k];
        __syncthreads();
        if (tid < 256) {
            float ssum = 0.f;
            #pragma unroll
            for (int r = 0; r < 16; ++r) ssum += colred[r * 256 + tid];
            atomicAdd(&csum[bz * 512 + cb0 + tid], ssum);
        }
    }
}

// ---------- v1 = 1.5*c0/tr - 0.5*c1 ----------
__global__ __launch_bounds__(512) void vkernA(const float* __restrict__ c0,
        const float* __restrict__ c1, const float* __restrict__ tr, float* __restrict__ v) {
    int b = blockIdx.x, c = threadIdx.x;
    float invt = 1.0f / tr[b];
    v[b * 512 + c] = 1.5f * c0[b * 512 + c] * invt - 0.5f * c1[b * 512 + c];
}

// ---------- v = 1.5*v - 0.5*vacc ----------
__global__ __launch_bounds__(512) void vkernB(const float* __restrict__ vacc, float* __restrict__ v) {
    int i = blockIdx.x * 512 + threadIdx.x;
    v[i] = 1.5f * v[i] - 0.5f * vacc[i];
}

// ---------- GEMV: out[b,:] (+)= w[b,:] @ M[b,:,:], M = bf16 hi+lo planes ----------
__global__ __launch_bounds__(512) void gemv_ml(
        const unsigned short* __restrict__ Mh, const unsigned short* __restrict__ Ml,
        const float* __restrict__ a0, const float* __restrict__ a1,
        const float* __restrict__ a2, const float* __restrict__ a3,
        float k0, float k1, float k2, float k3,
        float* __restrict__ wstore, float* __restrict__ out) {
    __shared__ float w[512];
    __shared__ __align__(16) float red[4][512];
    int b  = blockIdx.x & 31;
    int rc = blockIdx.x >> 5;                  // 0..15
    int t  = threadIdx.x;
    float wv = k0 * a0[b * 512 + t];
    if (a1) wv += k1 * a1[b * 512 + t];
    if (a2) wv += k2 * a2[b * 512 + t];
    if (a3) wv += k3 * a3[b * 512 + t];
    w[t] = wv;
    if (wstore != nullptr && rc == 0) wstore[b * 512 + t] = wv;
    __syncthreads();
    int rg = t >> 7, ct = t & 127;             // 4 row-groups x 128 col-threads (4 cols each)
    int row0 = rc * 32 + rg * 8;
    const unsigned short* ph = Mh + ((size_t)b * 512 + row0) * 512 + ct * 4;
    const unsigned short* pl = Ml + ((size_t)b * 512 + row0) * 512 + ct * 4;
    float4 acc = {0.f, 0.f, 0.f, 0.f};
    #pragma unroll
    for (int r = 0; r < 8; ++r) {
        ushort4 h = *(const ushort4*)(ph + (size_t)r * 512);
        ushort4 lo = *(const ushort4*)(pl + (size_t)r * 512);
        float wr = w[row0 + r];
        acc.x += wr * (bf2f(h.x) + bf2f(lo.x));
        acc.y += wr * (bf2f(h.y) + bf2f(lo.y));
        acc.z += wr * (bf2f(h.z) + bf2f(lo.z));
        acc.w += wr * (bf2f(h.w) + bf2f(lo.w));
    }
    *(float4*)&red[rg][ct * 4] = acc;
    __syncthreads();
    float s = red[0][t] + red[1][t] + red[2][t] + red[3][t];
    atomicAdd(&out[b * 512 + t], s);
}

// ---------- out = x * v5[ch]/512*sqrt(tr[b]);  v5 = 1.5v4 -1.125r1 +0.75r2 -0.28125u1 +0.1875u2 -0.03125u3 ----------
__global__ __launch_bounds__(256) void scale_x6(const float* __restrict__ x,
        const float* __restrict__ v4, const float* __restrict__ r1, const float* __restrict__ r2,
        const float* __restrict__ u1, const float* __restrict__ u2, const float* __restrict__ u3,
        const float* __restrict__ tr, float* __restrict__ out) {
    size_t i = (size_t)blockIdx.x * 256 + threadIdx.x;
    size_t ch = i / 196;
    int b = (int)(ch >> 9);
    float v5 = 1.5f * v4[ch] - 1.125f * r1[ch] + 0.75f * r2[ch]
             - 0.28125f * u1[ch] + 0.1875f * u2[ch] - 0.03125f * u3[ch];
    float sc = v5 * (1.0f / 512.0f) * sqrtf(tr[b]);
    float4 vv = ((const float4*)x)[i];
    vv.x *= sc; vv.y *= sc; vv.z *= sc; vv.w *= sc;
    ((float4*)out)[i] = vv;
}

extern "C" void kernel_launch(void* const* d_in, const int* in_sizes, int n_in,
                              void* d_out, int out_size, void* d_ws, size_t ws_size,
                              hipStream_t stream) {
    const float* x = (const float*)d_in[0];
    float* out = (float*)d_out;
    char* ws = (char*)d_ws;

    const size_t PLANE  = (size_t)32 * 512 * 512 * 2;   // 16.78 MB bf16 plane
    const size_t XPLANE = (size_t)32 * 512 * 800 * 2;   // 26.21 MB padded Xc plane
    const size_t SMALL  = (size_t)(2 << 20);            // small-vector region

    float* tr = (float*)ws;                              // 32 f (atomic)
    #define VEC(i) ((float*)(ws + 4096 + (size_t)(i) * 65536))
    float* c0    = VEC(0);  float* c1    = VEC(1);
    float* vacc0 = VEC(2);  float* vacc1 = VEC(3);
    float* v     = VEC(4);                               // evolving v1,v2
    float* v3    = VEC(5);  float* v4    = VEC(6);
    float* r1    = VEC(7);  float* r2    = VEC(8);
    float* p1    = VEC(9);  float* p2    = VEC(10); float* p3 = VEC(11);
    float* q1    = VEC(12); float* q2    = VEC(13); float* q3 = VEC(14);
    float* s1    = VEC(15); float* s2    = VEC(16); float* s3 = VEC(17);
    float* u1    = VEC(18); float* u2    = VEC(19); float* u3 = VEC(20);

    char* big = ws + SMALL;
    unsigned short* Ah = (unsigned short*)(big);                 // cov/M ping
    unsigned short* Al = (unsigned short*)(big + PLANE);
    char* R0 = big + 2 * PLANE;
    unsigned short* Xh = (unsigned short*)(R0);                  // dead after cov
    unsigned short* Xl = (unsigned short*)(R0 + XPLANE);
    unsigned short* Sh = (unsigned short*)(R0);                  // S = M^2 (overlaps X)
    unsigned short* Sl = (unsigned short*)(R0 + PLANE);
    size_t need = SMALL + 2 * PLANE + 2 * XPLANE + 2 * PLANE;
    unsigned short *Bh, *Bl;                                      // M pong
    if (ws_size >= need) {
        Bh = (unsigned short*)(R0 + 2 * XPLANE);
        Bl = (unsigned short*)(R0 + 2 * XPLANE + PLANE);
    } else {                                              // d_out scratch (51.4 MB >= 33.5 MB)
        Bh = (unsigned short*)out;
        Bl = (unsigned short*)out + (size_t)32 * 512 * 512;
    }

    hipMemsetAsync(ws, 0, 4096 + 21 * 65536, stream);    // zero tr + all vector slots (atomics)

    // 1) center + split
    center_convert<<<32 * 512, 256, 0, stream>>>(x, Xh, Xl);
    // 2) cov = Xc@Xc^T/784; fused trace + colsum(cov)->c0
    gemm_full<3, 1, 0><<<128, 512, 0, stream>>>(Xh, Xl, Xh, Xl, nullptr, nullptr, nullptr, nullptr,
                                                Ah, Al, tr, c0, nullptr, 800, 800, 1.0f / 784.0f);
    // 3) S0 = cov^2/tr^2 ; fused colsum(S0)->c1
    gemm_full<0, 1, 1><<<128, 512, 0, stream>>>(Ah, Al, Ah, Al, nullptr, nullptr, nullptr, nullptr,
                                                Sh, Sl, tr, c1, nullptr, 512, 512, 1.0f);
    // 4) v1 = 1.5*c0/tr - 0.5*c1
    vkernA<<<32, 512, 0, stream>>>(c0, c1, tr, v);
    // 5) M1 = 0.25(9*cov/tr - 6*S0 + cov@S0/tr) -> B ; fused vacc0 = v1 @ M1
    gemm_full<1, 2, 1><<<128, 512, 0, stream>>>(Ah, Al, Sh, Sl, Ah, Al, Sh, Sl,
                                                Bh, Bl, tr, vacc0, v, 512, 512, 1.0f);
    // 6) v2 = 1.5*v1 - 0.5*vacc0
    vkernB<<<32, 512, 0, stream>>>(vacc0, v);
    // 7) S1 = M1^2
    gemm_full<0, 0, 0><<<128, 512, 0, stream>>>(Bh, Bl, Bh, Bl, nullptr, nullptr, nullptr, nullptr,
                                                Sh, Sl, tr, nullptr, nullptr, 512, 512, 1.0f);
    // 8) M2 = 0.25(9*M1 - 6*S1 + M1@S1) -> A ; fused vacc1 = v2 @ M2
    gemm_full<1, 2, 0><<<128, 512, 0, stream>>>(Bh, Bl, Sh, Sl, Bh, Bl, Sh, Sl,
                                                Ah, Al, tr, vacc1, v, 512, 512, 1.0f);

    // 9) GEMV tail against M2 (Ah/Al): M3 = g(M2), M4 = g(M3) never materialized.
    //    g(x) = 0.25(9x - 6x^2 + x^3); x@g(M) = 2.25(xM) - 1.5(xM^2) + 0.25(xM^3).
    gemv_ml<<<512, 512, 0, stream>>>(Ah, Al, v,  vacc1, nullptr, nullptr, 1.5f, -0.5f, 0.f, 0.f, v3, p1);
    gemv_ml<<<512, 512, 0, stream>>>(Ah, Al, p1, nullptr, nullptr, nullptr, 1.f, 0.f, 0.f, 0.f, nullptr, p2);
    gemv_ml<<<512, 512, 0, stream>>>(Ah, Al, p2, nullptr, nullptr, nullptr, 1.f, 0.f, 0.f, 0.f, nullptr, p3);
    // v4 = 1.5*v3 - 0.5*(v3@M3) = 1.5v3 -1.125p1 +0.75p2 -0.125p3 ; q-chain: q_k = v4 @ M2^k
    gemv_ml<<<512, 512, 0, stream>>>(Ah, Al, v3, p1, p2, p3, 1.5f, -1.125f, 0.75f, -0.125f, v4, q1);
    gemv_ml<<<512, 512, 0, stream>>>(Ah, Al, q1, nullptr, nullptr, nullptr, 1.f, 0.f, 0.f, 0.f, nullptr, q2);
    gemv_ml<<<512, 512, 0, stream>>>(Ah, Al, q2, nullptr, nullptr, nullptr, 1.f, 0.f, 0.f, 0.f, nullptr, q3);
    // r1 = v4@M3 = 2.25q1 -1.5q2 +0.25q3 ; s-chain: s_k = r1 @ M2^k
    gemv_ml<<<512, 512, 0, stream>>>(Ah, Al, q1, q2, q3, nullptr, 2.25f, -1.5f, 0.25f, 0.f, r1, s1);
    gemv_ml<<<512, 512, 0, stream>>>(Ah, Al, s1, nullptr, nullptr, nullptr, 1.f, 0.f, 0.f, 0.f, nullptr, s2);
    gemv_ml<<<512, 512, 0, stream>>>(Ah, Al, s2, nullptr, nullptr, nullptr, 1.f, 0.f, 0.f, 0.f, nullptr, s3);
    // r2 = v4@M3^2 = r1@M3 = 2.25s1 -1.5s2 +0.25s3 ; u-chain: u_k = r2 @ M2^k
    gemv_ml<<<512, 512, 0, stream>>>(Ah, Al, s1, s2, s3, nullptr, 2.25f, -1.5f, 0.25f, 0.f, r2, u1);
    gemv_ml<<<512, 512, 0, stream>>>(Ah, Al, u1, nullptr, nullptr, nullptr, 1.f, 0.f, 0.f, 0.f, nullptr, u2);
    gemv_ml<<<512, 512, 0, stream>>>(Ah, Al, u2, nullptr, nullptr, nullptr, 1.f, 0.f, 0.f, 0.f, nullptr, u3);

    // 10) out = x * v5/512 * sqrt(tr); v5 combine fused (r3 = 2.25u1 -1.5u2 +0.25u3)
    scale_x6<<<12544, 256, 0, stream>>>(x, v4, r1, r2, u1, u2, u3, tr, out);
    #undef VEC
}

// Round 5
// 377.935 us; speedup vs baseline: 1.4346x; 1.4346x over previous
//
#include <hip/hip_runtime.h>
#include <math.h>

typedef short bf8 __attribute__((ext_vector_type(8)));   // 8 bf16 = 4 VGPRs
typedef float f4 __attribute__((ext_vector_type(4)));

__device__ inline unsigned short f2bf(float f) {          // RNE f32 -> bf16
    unsigned int u = __float_as_uint(f);
    u = u + 0x7fffu + ((u >> 16) & 1u);
    return (unsigned short)(u >> 16);
}
__device__ inline float bf2f(unsigned short h) {
    return __uint_as_float(((unsigned int)h) << 16);
}
__device__ inline void split_bf(float v, unsigned short& h, unsigned short& l) {
    h = f2bf(v);
    l = f2bf(v - bf2f(h));
}
__device__ inline unsigned int packbf(unsigned short a, unsigned short b) {
    return (unsigned int)a | ((unsigned int)b << 16);
}
__device__ inline void async16(const void* g, void* l) {
    __builtin_amdgcn_global_load_lds(
        (const __attribute__((address_space(1))) unsigned int*)g,
        (__attribute__((address_space(3))) unsigned int*)l, 16, 0, 0);
}

// ---------- fuse row-mean + center + bf16 hi/lo split (K padded 784->800 with zeros) ----------
__global__ __launch_bounds__(256) void center_convert(const float* __restrict__ x,
        unsigned short* __restrict__ Xh, unsigned short* __restrict__ Xl) {
    int row = blockIdx.x;                       // b*512 + c
    const float* xr = x + (size_t)row * 784;
    int t = threadIdx.x;
    float4 vv = {0.f, 0.f, 0.f, 0.f};
    if (t < 196) vv = *(const float4*)(xr + t * 4);
    float s = vv.x + vv.y + vv.z + vv.w;
    #pragma unroll
    for (int o = 32; o > 0; o >>= 1) s += __shfl_down(s, o, 64);
    __shared__ float red[4];
    int lane = t & 63, wv = t >> 6;
    if (lane == 0) red[wv] = s;
    __syncthreads();
    float m = (red[0] + red[1] + red[2] + red[3]) * (1.0f / 784.0f);
    if (t < 200) {
        ushort4 hh = {0, 0, 0, 0}, ll = {0, 0, 0, 0};
        if (t < 196) {
            split_bf(vv.x - m, hh.x, ll.x);
            split_bf(vv.y - m, hh.y, ll.y);
            split_bf(vv.z - m, hh.z, ll.z);
            split_bf(vv.w - m, hh.w, ll.w);
        }
        *(ushort4*)&Xh[(size_t)row * 800 + t * 4] = hh;
        *(ushort4*)&Xl[(size_t)row * 800 + t * 4] = ll;
    }
}

// ---------- full-grid bf16x3 NT GEMM, 128x128 tile, BK=32, 256 thr (4 waves, 64x64/wave) ----------
// LDS-TRAFFIC-CUT: 2x2 wave grid -> ds_read amplification A x2, B x2 (was x2/x4):
// 64 KB LDS-read per block per K-step (was 96 KB). Same 128^2 tile, dbuf, swizzle as the
// proven R1 kernel; grid 512 = 2 blocks/CU (8 waves/CU, 2/SIMD).
// MODE 0: C = A@B (S = M^2); ITER0: C *= invtr^2; CSUM=1 -> colsum
// MODE 1: C = 0.25(9*M*sc - 6*S + (A@B)*sc), sc = ITER0? invtr : 1; CSUM=2 -> vacc += vin.C
// MODE 3: C = (A@B)*cscale (cov); fused trace; CSUM=1 -> colsum(cov)
template<int MODE, int CSUM, int ITER0>
__global__ __launch_bounds__(256, 2) void gemm_full(
        const unsigned short* __restrict__ Ah, const unsigned short* __restrict__ Al,
        const unsigned short* __restrict__ Bh, const unsigned short* __restrict__ Bl,
        const unsigned short* __restrict__ Mh, const unsigned short* __restrict__ Ml,
        const unsigned short* __restrict__ Sh, const unsigned short* __restrict__ Sl,
        unsigned short* __restrict__ Ch, unsigned short* __restrict__ Cl,
        float* __restrict__ trp, float* __restrict__ csum, const float* __restrict__ vin,
        int K, int lda, float cscale) {
    __shared__ __align__(16) char smem[74240];   // 2x32768 staging | 128*129 f32 tile + colred
    unsigned short* stage = (unsigned short*)smem;
    float* tilef  = (float*)smem;
    float* colred = (float*)(smem + 66048);      // [16][128]

    int bid = blockIdx.x;
    int bz = bid & 31;
    int tt = bid >> 5;
    int by = tt >> 2, bx = tt & 3;

    size_t sAB = (size_t)512 * lda;
    size_t sC  = (size_t)512 * 512;
    const unsigned short* pAh = Ah + (size_t)bz * sAB;
    const unsigned short* pAl = Al + (size_t)bz * sAB;
    const unsigned short* pBh = Bh + (size_t)bz * sAB;
    const unsigned short* pBl = Bl + (size_t)bz * sAB;

    int tid = threadIdx.x;
    int w = tid >> 6, l = tid & 63;          // 4 waves
    int rb0 = by * 128, cb0 = bx * 128;

    // staging: wave w stages plane w (0:Ah 1:Al 2:Bh 3:Bl), 8 units of 1KB each.
    // plane chunk = 128 rows x 32 k x 2B = 8KB = 512 slots of 16B.
    // slot s = u*64 + l: row r = s>>2, k-slot g = (s&3)^((r>>1)&3) (pre-swizzled global
    // src, linear LDS dest = wave-uniform base + lane*16B).
    const unsigned short* gp = (w == 0) ? pAh : (w == 1) ? pAl : (w == 2) ? pBh : pBl;
    int rowbase = (w < 2) ? rb0 : cb0;
    size_t goff[8];
    int ldsoff[8];
    #pragma unroll
    for (int q = 0; q < 8; ++q) {
        int s0 = q * 64;                     // wave-uniform slot base within plane
        int s = s0 + l;
        int r = s >> 2, g = (s & 3) ^ ((r >> 1) & 3);
        goff[q] = (size_t)(rowbase + r) * lda + g * 8;
        ldsoff[q] = w * 4096 + s0 * 8;       // shorts, wave-uniform
    }

    f4 zero4 = {0.f, 0.f, 0.f, 0.f};
    f4 acc[4][4];
    #pragma unroll
    for (int i = 0; i < 4; ++i)
        #pragma unroll
        for (int j = 0; j < 4; ++j) acc[i][j] = zero4;

    int fr = l & 15, quad = l >> 4;
    int sw = quad ^ ((fr >> 1) & 3);
    int wr = w >> 1, wc = w & 1;             // wave tile: rows [wr*64,+64), cols [wc*64,+64)
    int NK = K >> 5;

    {   // prologue: stage chunk 0 into buf 0
        #pragma unroll
        for (int q = 0; q < 8; ++q) async16(gp + goff[q], stage + ldsoff[q]);
    }
    for (int ki = 0; ki < NK; ++ki) {
        __syncthreads();                     // drains buf[ki&1] (vmcnt0 + barrier)
        if (ki + 1 < NK) {
            int k0 = (ki + 1) << 5;
            unsigned short* sb2 = stage + ((ki + 1) & 1) * 16384;
            #pragma unroll
            for (int q = 0; q < 8; ++q) async16(gp + goff[q] + k0, sb2 + ldsoff[q]);
        }
        const unsigned short* sb = stage + (ki & 1) * 16384;
        bf8 ah[4], alo[4], bh[4], blo[4];
        #pragma unroll
        for (int i = 0; i < 4; ++i) {
            int oa = ((wr * 64 + i * 16 + fr) * 4 + sw) * 8;
            ah[i]  = *(const bf8*)&sb[0 * 4096 + oa];
            alo[i] = *(const bf8*)&sb[1 * 4096 + oa];
        }
        #pragma unroll
        for (int j = 0; j < 4; ++j) {
            int ob = ((wc * 64 + j * 16 + fr) * 4 + sw) * 8;
            bh[j]  = *(const bf8*)&sb[2 * 4096 + ob];
            blo[j] = *(const bf8*)&sb[3 * 4096 + ob];
        }
        #pragma unroll
        for (int i = 0; i < 4; ++i)
            #pragma unroll
            for (int j = 0; j < 4; ++j) {
                acc[i][j] = __builtin_amdgcn_mfma_f32_16x16x32_bf16(ah[i],  bh[j],  acc[i][j], 0, 0, 0);
                acc[i][j] = __builtin_amdgcn_mfma_f32_16x16x32_bf16(ah[i],  blo[j], acc[i][j], 0, 0, 0);
                acc[i][j] = __builtin_amdgcn_mfma_f32_16x16x32_bf16(alo[i], bh[j],  acc[i][j], 0, 0, 0);
            }
    }

    // ---- epilogue: acc -> f32 LDS tile [128][129] ----
    __syncthreads();
    #pragma unroll
    for (int i = 0; i < 4; ++i) {
        int rloc = wr * 64 + i * 16 + quad * 4;
        #pragma unroll
        for (int j = 0; j < 4; ++j) {
            int cloc = wc * 64 + j * 16 + fr;
            #pragma unroll
            for (int r = 0; r < 4; ++r) tilef[(rloc + r) * 129 + cloc] = acc[i][j][r];
        }
    }
    __syncthreads();

    float invtr_e = 1.0f;
    if ((MODE == 0 || MODE == 1) && ITER0) invtr_e = 1.0f / trp[bz];
    const float sc_g = (MODE == 3) ? cscale
                      : (MODE == 0 ? (ITER0 ? invtr_e * invtr_e : 1.0f)
                                   : (ITER0 ? invtr_e : 1.0f));

    unsigned short* qCh = Ch + (size_t)bz * sC;
    unsigned short* qCl = Cl + (size_t)bz * sC;
    const unsigned short* qMh = (MODE == 1) ? Mh + (size_t)bz * sC : nullptr;
    const unsigned short* qMl = (MODE == 1) ? Ml + (size_t)bz * sC : nullptr;
    const unsigned short* qSh = (MODE == 1) ? Sh + (size_t)bz * sC : nullptr;
    const unsigned short* qSl = (MODE == 1) ? Sl + (size_t)bz * sC : nullptr;

    int lr = tid >> 4, lc0 = (tid & 15) * 8;     // lr 0..15
    float cp[8] = {0.f, 0.f, 0.f, 0.f, 0.f, 0.f, 0.f, 0.f};
    #pragma unroll
    for (int p = 0; p < 8; ++p) {
        int row = lr + p * 16;                   // 0..127
        int grow = rb0 + row, gcol = cb0 + lc0;
        float vv[8];
        #pragma unroll
        for (int k = 0; k < 8; ++k) vv[k] = tilef[row * 129 + lc0 + k];
        size_t gaddr = (size_t)grow * 512 + gcol;
        if (MODE == 3 || MODE == 0) {
            #pragma unroll
            for (int k = 0; k < 8; ++k) vv[k] *= sc_g;
        }
        if (MODE == 1) {
            uint4 mh = *(const uint4*)&qMh[gaddr], ml = *(const uint4*)&qMl[gaddr];
            uint4 sh = *(const uint4*)&qSh[gaddr], sl = *(const uint4*)&qSl[gaddr];
            const unsigned int* mhp = (const unsigned int*)&mh; const unsigned int* mlp = (const unsigned int*)&ml;
            const unsigned int* shp = (const unsigned int*)&sh; const unsigned int* slp = (const unsigned int*)&sl;
            #pragma unroll
            for (int k = 0; k < 8; ++k) {
                unsigned int hm = mhp[k >> 1], lm = mlp[k >> 1], hs = shp[k >> 1], ls = slp[k >> 1];
                float mval = bf2f((unsigned short)((k & 1) ? (hm >> 16) : (hm & 0xffffu)))
                           + bf2f((unsigned short)((k & 1) ? (lm >> 16) : (lm & 0xffffu)));
                float sval = bf2f((unsigned short)((k & 1) ? (hs >> 16) : (hs & 0xffffu)))
                           + bf2f((unsigned short)((k & 1) ? (ls >> 16) : (ls & 0xffffu)));
                vv[k] = 0.25f * (9.0f * mval * sc_g - 6.0f * sval + vv[k] * sc_g);
            }
        }
        unsigned short h[8], lo[8];
        #pragma unroll
        for (int k = 0; k < 8; ++k) split_bf(vv[k], h[k], lo[k]);
        uint4 uh, ul;
        uh.x = packbf(h[0], h[1]); uh.y = packbf(h[2], h[3]); uh.z = packbf(h[4], h[5]); uh.w = packbf(h[6], h[7]);
        ul.x = packbf(lo[0], lo[1]); ul.y = packbf(lo[2], lo[3]); ul.z = packbf(lo[4], lo[5]); ul.w = packbf(lo[6], lo[7]);
        *(uint4*)&qCh[gaddr] = uh;
        *(uint4*)&qCl[gaddr] = ul;
        if (MODE == 3 && bx == by) {            // trace (diag tiles)
            int d = row - lc0;
            if (d >= 0 && d < 8) atomicAdd(&trp[bz], vv[d]);
        }
        if (CSUM == 1) {
            #pragma unroll
            for (int k = 0; k < 8; ++k) cp[k] += vv[k];
        } else if (CSUM == 2) {
            float wgt = vin[bz * 512 + grow];
            #pragma unroll
            for (int k = 0; k < 8; ++k) cp[k] += wgt * vv[k];
        }
    }
    if (CSUM) {     // 16 row-groups x 128 cols -> 1 atomic/col
        __syncthreads();
        #pragma unroll
        for (int k = 0; k < 8; ++k) colred[lr * 128 + lc0 + k] = cp[k];
        __syncthreads();
        if (tid < 128) {
            float s = 0.f;
            #pragma unroll
            for (int r = 0; r < 16; ++r) s += colred[r * 128 + tid];
            atomicAdd(&csum[bz * 512 + cb0 + tid], s);
        }
    }
}

// ---------- v1 = 1.5*c0/tr - 0.5*c1 ----------
__global__ __launch_bounds__(512) void vkernA(const float* __restrict__ c0,
        const float* __restrict__ c1, const float* __restrict__ tr, float* __restrict__ v) {
    int b = blockIdx.x, c = threadIdx.x;
    float invt = 1.0f / tr[b];
    v[b * 512 + c] = 1.5f * c0[b * 512 + c] * invt - 0.5f * c1[b * 512 + c];
}

// ---------- v = 1.5*v - 0.5*vacc ----------
__global__ __launch_bounds__(512) void vkernB(const float* __restrict__ vacc, float* __restrict__ v) {
    int i = blockIdx.x * 512 + threadIdx.x;
    v[i] = 1.5f * v[i] - 0.5f * vacc[i];
}

// ---------- GEMV: out[b,:] (+)= w[b,:] @ M[b,:,:], M = bf16 hi+lo planes ----------
__global__ __launch_bounds__(512) void gemv_ml(
        const unsigned short* __restrict__ Mh, const unsigned short* __restrict__ Ml,
        const float* __restrict__ a0, const float* __restrict__ a1,
        const float* __restrict__ a2, const float* __restrict__ a3,
        float k0, float k1, float k2, float k3,
        float* __restrict__ wstore, float* __restrict__ out) {
    __shared__ float w[512];
    __shared__ __align__(16) float red[4][512];
    int b  = blockIdx.x & 31;
    int rc = blockIdx.x >> 5;                  // 0..15
    int t  = threadIdx.x;
    float wv = k0 * a0[b * 512 + t];
    if (a1) wv += k1 * a1[b * 512 + t];
    if (a2) wv += k2 * a2[b * 512 + t];
    if (a3) wv += k3 * a3[b * 512 + t];
    w[t] = wv;
    if (wstore != nullptr && rc == 0) wstore[b * 512 + t] = wv;
    __syncthreads();
    int rg = t >> 7, ct = t & 127;             // 4 row-groups x 128 col-threads (4 cols each)
    int row0 = rc * 32 + rg * 8;
    const unsigned short* ph = Mh + ((size_t)b * 512 + row0) * 512 + ct * 4;
    const unsigned short* pl = Ml + ((size_t)b * 512 + row0) * 512 + ct * 4;
    float4 acc = {0.f, 0.f, 0.f, 0.f};
    #pragma unroll
    for (int r = 0; r < 8; ++r) {
        ushort4 h = *(const ushort4*)(ph + (size_t)r * 512);
        ushort4 lo = *(const ushort4*)(pl + (size_t)r * 512);
        float wr = w[row0 + r];
        acc.x += wr * (bf2f(h.x) + bf2f(lo.x));
        acc.y += wr * (bf2f(h.y) + bf2f(lo.y));
        acc.z += wr * (bf2f(h.z) + bf2f(lo.z));
        acc.w += wr * (bf2f(h.w) + bf2f(lo.w));
    }
    *(float4*)&red[rg][ct * 4] = acc;
    __syncthreads();
    float s = red[0][t] + red[1][t] + red[2][t] + red[3][t];
    atomicAdd(&out[b * 512 + t], s);
}

// ---------- out = x * v5[ch]/512*sqrt(tr[b]);  v5 = 1.5v4 -1.125r1 +0.75r2 -0.28125u1 +0.1875u2 -0.03125u3 ----------
__global__ __launch_bounds__(256) void scale_x6(const float* __restrict__ x,
        const float* __restrict__ v4, const float* __restrict__ r1, const float* __restrict__ r2,
        const float* __restrict__ u1, const float* __restrict__ u2, const float* __restrict__ u3,
        const float* __restrict__ tr, float* __restrict__ out) {
    size_t i = (size_t)blockIdx.x * 256 + threadIdx.x;
    size_t ch = i / 196;
    int b = (int)(ch >> 9);
    float v5 = 1.5f * v4[ch] - 1.125f * r1[ch] + 0.75f * r2[ch]
             - 0.28125f * u1[ch] + 0.1875f * u2[ch] - 0.03125f * u3[ch];
    float sc = v5 * (1.0f / 512.0f) * sqrtf(tr[b]);
    float4 vv = ((const float4*)x)[i];
    vv.x *= sc; vv.y *= sc; vv.z *= sc; vv.w *= sc;
    ((float4*)out)[i] = vv;
}

extern "C" void kernel_launch(void* const* d_in, const int* in_sizes, int n_in,
                              void* d_out, int out_size, void* d_ws, size_t ws_size,
                              hipStream_t stream) {
    const float* x = (const float*)d_in[0];
    float* out = (float*)d_out;
    char* ws = (char*)d_ws;

    const size_t PLANE  = (size_t)32 * 512 * 512 * 2;   // 16.78 MB bf16 plane
    const size_t XPLANE = (size_t)32 * 512 * 800 * 2;   // 26.21 MB padded Xc plane
    const size_t SMALL  = (size_t)(2 << 20);            // small-vector region

    float* tr = (float*)ws;                              // 32 f (atomic)
    #define VEC(i) ((float*)(ws + 4096 + (size_t)(i) * 65536))
    float* c0    = VEC(0);  float* c1    = VEC(1);
    float* vacc0 = VEC(2);  float* vacc1 = VEC(3);
    float* v     = VEC(4);                               // evolving v1,v2
    float* v3    = VEC(5);  float* v4    = VEC(6);
    float* r1    = VEC(7);  float* r2    = VEC(8);
    float* p1    = VEC(9);  float* p2    = VEC(10); float* p3 = VEC(11);
    float* q1    = VEC(12); float* q2    = VEC(13); float* q3 = VEC(14);
    float* s1    = VEC(15); float* s2    = VEC(16); float* s3 = VEC(17);
    float* u1    = VEC(18); float* u2    = VEC(19); float* u3 = VEC(20);

    char* big = ws + SMALL;
    unsigned short* Ah = (unsigned short*)(big);                 // cov/M ping
    unsigned short* Al = (unsigned short*)(big + PLANE);
    char* R0 = big + 2 * PLANE;
    unsigned short* Xh = (unsigned short*)(R0);                  // dead after cov
    unsigned short* Xl = (unsigned short*)(R0 + XPLANE);
    unsigned short* Sh = (unsigned short*)(R0);                  // S = M^2 (overlaps X)
    unsigned short* Sl = (unsigned short*)(R0 + PLANE);
    size_t need = SMALL + 2 * PLANE + 2 * XPLANE + 2 * PLANE;
    unsigned short *Bh, *Bl;                                      // M pong
    if (ws_size >= need) {
        Bh = (unsigned short*)(R0 + 2 * XPLANE);
        Bl = (unsigned short*)(R0 + 2 * XPLANE + PLANE);
    } else {                                              // d_out scratch (51.4 MB >= 33.5 MB)
        Bh = (unsigned short*)out;
        Bl = (unsigned short*)out + (size_t)32 * 512 * 512;
    }

    hipMemsetAsync(ws, 0, 4096 + 21 * 65536, stream);    // zero tr + all vector slots (atomics)

    // 1) center + split
    center_convert<<<32 * 512, 256, 0, stream>>>(x, Xh, Xl);
    // 2) cov = Xc@Xc^T/784; fused trace + colsum(cov)->c0
    gemm_full<3, 1, 0><<<512, 256, 0, stream>>>(Xh, Xl, Xh, Xl, nullptr, nullptr, nullptr, nullptr,
                                                Ah, Al, tr, c0, nullptr, 800, 800, 1.0f / 784.0f);
    // 3) S0 = cov^2/tr^2 ; fused colsum(S0)->c1
    gemm_full<0, 1, 1><<<512, 256, 0, stream>>>(Ah, Al, Ah, Al, nullptr, nullptr, nullptr, nullptr,
                                                Sh, Sl, tr, c1, nullptr, 512, 512, 1.0f);
    // 4) v1 = 1.5*c0/tr - 0.5*c1
    vkernA<<<32, 512, 0, stream>>>(c0, c1, tr, v);
    // 5) M1 = 0.25(9*cov/tr - 6*S0 + cov@S0/tr) -> B ; fused vacc0 = v1 @ M1
    gemm_full<1, 2, 1><<<512, 256, 0, stream>>>(Ah, Al, Sh, Sl, Ah, Al, Sh, Sl,
                                                Bh, Bl, tr, vacc0, v, 512, 512, 1.0f);
    // 6) v2 = 1.5*v1 - 0.5*vacc0
    vkernB<<<32, 512, 0, stream>>>(vacc0, v);
    // 7) S1 = M1^2
    gemm_full<0, 0, 0><<<512, 256, 0, stream>>>(Bh, Bl, Bh, Bl, nullptr, nullptr, nullptr, nullptr,
                                                Sh, Sl, tr, nullptr, nullptr, 512, 512, 1.0f);
    // 8) M2 = 0.25(9*M1 - 6*S1 + M1@S1) -> A ; fused vacc1 = v2 @ M2
    gemm_full<1, 2, 0><<<512, 256, 0, stream>>>(Bh, Bl, Sh, Sl, Bh, Bl, Sh, Sl,
                                                Ah, Al, tr, vacc1, v, 512, 512, 1.0f);

    // 9) GEMV tail against M2 (Ah/Al): M3 = g(M2), M4 = g(M3) never materialized.
    //    g(x) = 0.25(9x - 6x^2 + x^3); x@g(M) = 2.25(xM) - 1.5(xM^2) + 0.25(xM^3).
    gemv_ml<<<512, 512, 0, stream>>>(Ah, Al, v,  vacc1, nullptr, nullptr, 1.5f, -0.5f, 0.f, 0.f, v3, p1);
    gemv_ml<<<512, 512, 0, stream>>>(Ah, Al, p1, nullptr, nullptr, nullptr, 1.f, 0.f, 0.f, 0.f, nullptr, p2);
    gemv_ml<<<512, 512, 0, stream>>>(Ah, Al, p2, nullptr, nullptr, nullptr, 1.f, 0.f, 0.f, 0.f, nullptr, p3);
    // v4 = 1.5*v3 - 0.5*(v3@M3) = 1.5v3 -1.125p1 +0.75p2 -0.125p3 ; q-chain: q_k = v4 @ M2^k
    gemv_ml<<<512, 512, 0, stream>>>(Ah, Al, v3, p1, p2, p3, 1.5f, -1.125f, 0.75f, -0.125f, v4, q1);
    gemv_ml<<<512, 512, 0, stream>>>(Ah, Al, q1, nullptr, nullptr, nullptr, 1.f, 0.f, 0.f, 0.f, nullptr, q2);
    gemv_ml<<<512, 512, 0, stream>>>(Ah, Al, q2, nullptr, nullptr, nullptr, 1.f, 0.f, 0.f, 0.f, nullptr, q3);
    // r1 = v4@M3 = 2.25q1 -1.5q2 +0.25q3 ; s-chain: s_k = r1 @ M2^k
    gemv_ml<<<512, 512, 0, stream>>>(Ah, Al, q1, q2, q3, nullptr, 2.25f, -1.5f, 0.25f, 0.f, r1, s1);
    gemv_ml<<<512, 512, 0, stream>>>(Ah, Al, s1, nullptr, nullptr, nullptr, 1.f, 0.f, 0.f, 0.f, nullptr, s2);
    gemv_ml<<<512, 512, 0, stream>>>(Ah, Al, s2, nullptr, nullptr, nullptr, 1.f, 0.f, 0.f, 0.f, nullptr, s3);
    // r2 = v4@M3^2 = r1@M3 = 2.25s1 -1.5s2 +0.25s3 ; u-chain: u_k = r2 @ M2^k
    gemv_ml<<<512, 512, 0, stream>>>(Ah, Al, s1, s2, s3, nullptr, 2.25f, -1.5f, 0.25f, 0.f, r2, u1);
    gemv_ml<<<512, 512, 0, stream>>>(Ah, Al, u1, nullptr, nullptr, nullptr, 1.f, 0.f, 0.f, 0.f, nullptr, u2);
    gemv_ml<<<512, 512, 0, stream>>>(Ah, Al, u2, nullptr, nullptr, nullptr, 1.f, 0.f, 0.f, 0.f, nullptr, u3);

    // 10) out = x * v5/512 * sqrt(tr); v5 combine fused (r3 = 2.25u1 -1.5u2 +0.25u3)
    scale_x6<<<12544, 256, 0, stream>>>(x, v4, r1, r2, u1, u2, u3, tr, out);
    #undef VEC
}

// Round 6
// 375.212 us; speedup vs baseline: 1.4450x; 1.0073x over previous
//
#include <hip/hip_runtime.h>
#include <math.h>

typedef short bf8 __attribute__((ext_vector_type(8)));   // 8 bf16 = 4 VGPRs
typedef float f4 __attribute__((ext_vector_type(4)));

__device__ inline unsigned short f2bf(float f) {          // RNE f32 -> bf16
    unsigned int u = __float_as_uint(f);
    u = u + 0x7fffu + ((u >> 16) & 1u);
    return (unsigned short)(u >> 16);
}
__device__ inline float bf2f(unsigned short h) {
    return __uint_as_float(((unsigned int)h) << 16);
}
__device__ inline void split_bf(float v, unsigned short& h, unsigned short& l) {
    h = f2bf(v);
    l = f2bf(v - bf2f(h));
}
__device__ inline unsigned int packbf(unsigned short a, unsigned short b) {
    return (unsigned int)a | ((unsigned int)b << 16);
}
__device__ inline void async16(const void* g, void* l) {
    __builtin_amdgcn_global_load_lds(
        (const __attribute__((address_space(1))) unsigned int*)g,
        (__attribute__((address_space(3))) unsigned int*)l, 16, 0, 0);
}

// upper-triangle 64x128 chunk table (per batch): 12 strict-upper (write T and T^T),
// 8 diagonal-straddling j = floor(i/2) (write T only). Coverage of full 512^2 verified.
__constant__ int CI20[20] = {0,0,0, 1,1,1, 2,2, 3,3, 4,5,   0,1,2,3,4,5,6,7};
__constant__ int CJ20[20] = {1,2,3, 1,2,3, 2,3, 2,3, 3,3,   0,0,1,1,2,2,3,3};

// ---------- fuse row-mean + center + bf16 hi/lo split (K padded 784->800 with zeros) ----------
__global__ __launch_bounds__(256) void center_convert(const float* __restrict__ x,
        unsigned short* __restrict__ Xh, unsigned short* __restrict__ Xl) {
    int row = blockIdx.x;                       // b*512 + c
    const float* xr = x + (size_t)row * 784;
    int t = threadIdx.x;
    float4 vv = {0.f, 0.f, 0.f, 0.f};
    if (t < 196) vv = *(const float4*)(xr + t * 4);
    float s = vv.x + vv.y + vv.z + vv.w;
    #pragma unroll
    for (int o = 32; o > 0; o >>= 1) s += __shfl_down(s, o, 64);
    __shared__ float red[4];
    int lane = t & 63, wv = t >> 6;
    if (lane == 0) red[wv] = s;
    __syncthreads();
    float m = (red[0] + red[1] + red[2] + red[3]) * (1.0f / 784.0f);
    if (t < 200) {
        ushort4 hh = {0, 0, 0, 0}, ll = {0, 0, 0, 0};
        if (t < 196) {
            split_bf(vv.x - m, hh.x, ll.x);
            split_bf(vv.y - m, hh.y, ll.y);
            split_bf(vv.z - m, hh.z, ll.z);
            split_bf(vv.w - m, hh.w, ll.w);
        }
        *(ushort4*)&Xh[(size_t)row * 800 + t * 4] = hh;
        *(ushort4*)&Xl[(size_t)row * 800 + t * 4] = ll;
    }
}

// ---------- SYMMETRIC bf16x3 NT GEMM: 64x128 upper-tri chunks, BK=32, 256 thr (4 waves) ----------
// All chain matrices are symmetric -> compute only upper-triangle chunks (62.5% of tiles).
// Strict-upper chunks write T and T^T (M,S symmetric so transposed MODE1 transform reuses
// same addresses); straddling chunks write once. grid 640 = 20 chunks x 32 batches
// (bz = bid&31 fastest => batch bz on XCD bz%8). LDS 48KB -> 3 blocks/CU, 12 waves/CU.
// MODE 0: C = A@B (S = M^2); ITER0: C *= invtr^2; CSUM=1 -> colsum
// MODE 1: C = 0.25(9*M*sc - 6*S + (A@B)*sc), sc = ITER0? invtr : 1; CSUM=2 -> vacc += vin.C
// MODE 3: C = (A@B)*cscale (cov); fused trace; CSUM=1 -> colsum(cov)
template<int MODE, int CSUM, int ITER0>
__global__ __launch_bounds__(256, 3) void gemm_sym(
        const unsigned short* __restrict__ Ah, const unsigned short* __restrict__ Al,
        const unsigned short* __restrict__ Bh, const unsigned short* __restrict__ Bl,
        const unsigned short* __restrict__ Mh, const unsigned short* __restrict__ Ml,
        const unsigned short* __restrict__ Sh, const unsigned short* __restrict__ Sl,
        unsigned short* __restrict__ Ch, unsigned short* __restrict__ Cl,
        float* __restrict__ trp, float* __restrict__ csum, const float* __restrict__ vin,
        int K, int lda, float cscale) {
    // staging: 2 bufs x 12288 shorts (Ah 2048 | Al 2048 | Bh 4096 | Bl 4096) = 48KB
    // epilogue overlay: tilef [64][129] f32 (33024 B) + colred [16][128] f32 @33024
    __shared__ __align__(16) char smem[49152];
    unsigned short* stage = (unsigned short*)smem;
    float* tilef  = (float*)smem;
    float* colred = (float*)(smem + 33024);

    int bid = blockIdx.x;
    int bz = bid & 31;
    int chunk = bid >> 5;                    // 0..19
    int rb0 = CI20[chunk] * 64, cb0 = CJ20[chunk] * 128;
    bool strict = chunk < 12;

    size_t sAB = (size_t)512 * lda;
    size_t sC  = (size_t)512 * 512;
    const unsigned short* pAh = Ah + (size_t)bz * sAB;
    const unsigned short* pAl = Al + (size_t)bz * sAB;
    const unsigned short* pBh = Bh + (size_t)bz * sAB;
    const unsigned short* pBl = Bl + (size_t)bz * sAB;

    int tid = threadIdx.x;
    int w = tid >> 6, l = tid & 63;          // 4 waves

    // staging: 24 units of 1KB (64 lanes x 16B); wave w stages units [w*6, w*6+6).
    // units 0..3: Ah, 4..7: Al, 8..15: Bh, 16..23: Bl.
    // plane slot s: row r = s>>2, k-slot g = (s&3)^((r>>1)&3) (pre-swizzled global src,
    // linear LDS dest).
    size_t goff[6]; int ldsoff[6]; const unsigned short* gq[6];
    #pragma unroll
    for (int q = 0; q < 6; ++q) {
        int u = w * 6 + q;
        int p = (u < 4) ? 0 : (u < 8) ? 1 : (u < 16) ? 2 : 3;
        int ub = u - ((p == 0) ? 0 : (p == 1) ? 4 : (p == 2) ? 8 : 16);
        gq[q] = (p == 0) ? pAh : (p == 1) ? pAl : (p == 2) ? pBh : pBl;
        int rowbase = (p < 2) ? rb0 : cb0;
        int s = ub * 64 + l;
        int r = s >> 2, g = (s & 3) ^ ((r >> 1) & 3);
        goff[q] = (size_t)(rowbase + r) * lda + g * 8;
        ldsoff[q] = ((p == 0) ? 0 : (p == 1) ? 2048 : (p == 2) ? 4096 : 8192)
                    + ub * 512 + l * 8;      // shorts
    }

    f4 zero4 = {0.f, 0.f, 0.f, 0.f};
    f4 acc[2][4];
    #pragma unroll
    for (int i = 0; i < 2; ++i)
        #pragma unroll
        for (int j = 0; j < 4; ++j) acc[i][j] = zero4;

    int fr = l & 15, quad = l >> 4;
    int sw = quad ^ ((fr >> 1) & 3);
    int wr = w >> 1, wc = w & 1;             // wave tile: rows [wr*32,+32), cols [wc*64,+64)
    int NK = K >> 5;

    {   // prologue: stage chunk 0 into buf 0
        #pragma unroll
        for (int q = 0; q < 6; ++q) async16(gq[q] + goff[q], stage + ldsoff[q]);
    }
    for (int ki = 0; ki < NK; ++ki) {
        __syncthreads();                     // drains buf[ki&1] (vmcnt0 + barrier)
        if (ki + 1 < NK) {
            int k0 = (ki + 1) << 5;
            unsigned short* sb2 = stage + ((ki + 1) & 1) * 12288;
            #pragma unroll
            for (int q = 0; q < 6; ++q) async16(gq[q] + goff[q] + k0, sb2 + ldsoff[q]);
        }
        const unsigned short* sb = stage + (ki & 1) * 12288;
        bf8 ah[2], alo[2], bh[4], blo[4];
        #pragma unroll
        for (int i = 0; i < 2; ++i) {
            int oa = ((wr * 32 + i * 16 + fr) * 4 + sw) * 8;
            ah[i]  = *(const bf8*)&sb[oa];
            alo[i] = *(const bf8*)&sb[2048 + oa];
        }
        #pragma unroll
        for (int j = 0; j < 4; ++j) {
            int ob = ((wc * 64 + j * 16 + fr) * 4 + sw) * 8;
            bh[j]  = *(const bf8*)&sb[4096 + ob];
            blo[j] = *(const bf8*)&sb[8192 + ob];
        }
        #pragma unroll
        for (int i = 0; i < 2; ++i)
            #pragma unroll
            for (int j = 0; j < 4; ++j) {
                acc[i][j] = __builtin_amdgcn_mfma_f32_16x16x32_bf16(ah[i],  bh[j],  acc[i][j], 0, 0, 0);
                acc[i][j] = __builtin_amdgcn_mfma_f32_16x16x32_bf16(ah[i],  blo[j], acc[i][j], 0, 0, 0);
                acc[i][j] = __builtin_amdgcn_mfma_f32_16x16x32_bf16(alo[i], bh[j],  acc[i][j], 0, 0, 0);
            }
    }

    // ---- epilogue: acc -> f32 LDS tile [64][129] ----
    __syncthreads();
    #pragma unroll
    for (int i = 0; i < 2; ++i) {
        int rloc = wr * 32 + i * 16 + quad * 4;
        #pragma unroll
        for (int j = 0; j < 4; ++j) {
            int cloc = wc * 64 + j * 16 + fr;
            #pragma unroll
            for (int r = 0; r < 4; ++r) tilef[(rloc + r) * 129 + cloc] = acc[i][j][r];
        }
    }
    __syncthreads();

    float invtr_e = 1.0f;
    if ((MODE == 0 || MODE == 1) && ITER0) invtr_e = 1.0f / trp[bz];
    const float sc_g = (MODE == 3) ? cscale
                      : (MODE == 0 ? (ITER0 ? invtr_e * invtr_e : 1.0f)
                                   : (ITER0 ? invtr_e : 1.0f));

    unsigned short* qCh = Ch + (size_t)bz * sC;
    unsigned short* qCl = Cl + (size_t)bz * sC;
    const unsigned short* qMh = (MODE == 1) ? Mh + (size_t)bz * sC : nullptr;
    const unsigned short* qMl = (MODE == 1) ? Ml + (size_t)bz * sC : nullptr;
    const unsigned short* qSh = (MODE == 1) ? Sh + (size_t)bz * sC : nullptr;
    const unsigned short* qSl = (MODE == 1) ? Sl + (size_t)bz * sC : nullptr;

    // ---- pass 1: normal orientation (all chunks) + col partials + row-sums (strict) ----
    int lr = tid >> 4, lc0 = (tid & 15) * 8;     // lr 0..15
    float cp[8] = {0.f, 0.f, 0.f, 0.f, 0.f, 0.f, 0.f, 0.f};
    #pragma unroll
    for (int p = 0; p < 4; ++p) {
        int row = lr + p * 16;                   // 0..63
        int grow = rb0 + row, gcol = cb0 + lc0;
        float vv[8];
        #pragma unroll
        for (int k = 0; k < 8; ++k) vv[k] = tilef[row * 129 + lc0 + k];
        size_t gaddr = (size_t)grow * 512 + gcol;
        if (MODE == 3 || MODE == 0) {
            #pragma unroll
            for (int k = 0; k < 8; ++k) vv[k] *= sc_g;
        }
        if (MODE == 1) {
            uint4 mh = *(const uint4*)&qMh[gaddr], ml = *(const uint4*)&qMl[gaddr];
            uint4 sh = *(const uint4*)&qSh[gaddr], sl = *(const uint4*)&qSl[gaddr];
            const unsigned int* mhp = (const unsigned int*)&mh; const unsigned int* mlp = (const unsigned int*)&ml;
            const unsigned int* shp = (const unsigned int*)&sh; const unsigned int* slp = (const unsigned int*)&sl;
            #pragma unroll
            for (int k = 0; k < 8; ++k) {
                unsigned int hm = mhp[k >> 1], lm = mlp[k >> 1], hs = shp[k >> 1], ls = slp[k >> 1];
                float mval = bf2f((unsigned short)((k & 1) ? (hm >> 16) : (hm & 0xffffu)))
                           + bf2f((unsigned short)((k & 1) ? (lm >> 16) : (lm & 0xffffu)));
                float sval = bf2f((unsigned short)((k & 1) ? (hs >> 16) : (hs & 0xffffu)))
                           + bf2f((unsigned short)((k & 1) ? (ls >> 16) : (ls & 0xffffu)));
                vv[k] = 0.25f * (9.0f * mval * sc_g - 6.0f * sval + vv[k] * sc_g);
            }
        }
        unsigned short h[8], lo[8];
        #pragma unroll
        for (int k = 0; k < 8; ++k) split_bf(vv[k], h[k], lo[k]);
        uint4 uh, ul;
        uh.x = packbf(h[0], h[1]); uh.y = packbf(h[2], h[3]); uh.z = packbf(h[4], h[5]); uh.w = packbf(h[6], h[7]);
        ul.x = packbf(lo[0], lo[1]); ul.y = packbf(lo[2], lo[3]); ul.z = packbf(lo[4], lo[5]); ul.w = packbf(lo[6], lo[7]);
        *(uint4*)&qCh[gaddr] = uh;
        *(uint4*)&qCl[gaddr] = ul;
        if (MODE == 3 && !strict) {              // trace lives in straddling chunks
            int dd = grow - gcol;
            if (dd >= 0 && dd < 8) atomicAdd(&trp[bz], vv[dd]);
        }
        if (CSUM == 1) {
            #pragma unroll
            for (int k = 0; k < 8; ++k) cp[k] += vv[k];
        } else if (CSUM == 2) {
            float wgt = vin[bz * 512 + grow];
            #pragma unroll
            for (int k = 0; k < 8; ++k) cp[k] += wgt * vv[k];
        }
        if (CSUM && strict) {                    // mirrored colsum via row-sum of T
            float rs = 0.f;
            if (CSUM == 1) {
                #pragma unroll
                for (int k = 0; k < 8; ++k) rs += vv[k];
            } else {
                #pragma unroll
                for (int k = 0; k < 8; ++k) rs += vin[bz * 512 + gcol + k] * vv[k];
            }
            #pragma unroll
            for (int o = 8; o > 0; o >>= 1) rs += __shfl_down(rs, o, 16);
            if ((tid & 15) == 0) atomicAdd(&csum[bz * 512 + grow], rs);
        }
    }

    // ---- pass 2 (strict only): transposed write C[cb0+c][rb0+r] = T[r][c] (M,S symmetric) ----
    if (strict) {
        int c2 = tid >> 1, hh2 = tid & 1;        // c2 0..127
        int grow2 = cb0 + c2;
        #pragma unroll
        for (int p2 = 0; p2 < 4; ++p2) {
            int col0 = hh2 * 8 + p2 * 16;        // 0..56, covers 0..63
            int gcol2 = rb0 + col0;
            float vv[8];
            #pragma unroll
            for (int k = 0; k < 8; ++k) vv[k] = tilef[(col0 + k) * 129 + c2];
            size_t gaddr = (size_t)grow2 * 512 + gcol2;
            if (MODE == 3 || MODE == 0) {
                #pragma unroll
                for (int k = 0; k < 8; ++k) vv[k] *= sc_g;
            }
            if (MODE == 1) {
                uint4 mh = *(const uint4*)&qMh[gaddr], ml = *(const uint4*)&qMl[gaddr];
                uint4 sh = *(const uint4*)&qSh[gaddr], sl = *(const uint4*)&qSl[gaddr];
                const unsigned int* mhp = (const unsigned int*)&mh; const unsigned int* mlp = (const unsigned int*)&ml;
                const unsigned int* shp = (const unsigned int*)&sh; const unsigned int* slp = (const unsigned int*)&sl;
                #pragma unroll
                for (int k = 0; k < 8; ++k) {
                    unsigned int hm = mhp[k >> 1], lm = mlp[k >> 1], hs = shp[k >> 1], ls = slp[k >> 1];
                    float mval = bf2f((unsigned short)((k & 1) ? (hm >> 16) : (hm & 0xffffu)))
                               + bf2f((unsigned short)((k & 1) ? (lm >> 16) : (lm & 0xffffu)));
                    float sval = bf2f((unsigned short)((k & 1) ? (hs >> 16) : (hs & 0xffffu)))
                               + bf2f((unsigned short)((k & 1) ? (ls >> 16) : (ls & 0xffffu)));
                    vv[k] = 0.25f * (9.0f * mval * sc_g - 6.0f * sval + vv[k] * sc_g);
                }
            }
            unsigned short h[8], lo[8];
            #pragma unroll
            for (int k = 0; k < 8; ++k) split_bf(vv[k], h[k], lo[k]);
            uint4 uh, ul;
            uh.x = packbf(h[0], h[1]); uh.y = packbf(h[2], h[3]); uh.z = packbf(h[4], h[5]); uh.w = packbf(h[6], h[7]);
            ul.x = packbf(lo[0], lo[1]); ul.y = packbf(lo[2], lo[3]); ul.z = packbf(lo[4], lo[5]); ul.w = packbf(lo[6], lo[7]);
            *(uint4*)&qCh[gaddr] = uh;
            *(uint4*)&qCl[gaddr] = ul;
        }
    }

    if (CSUM) {     // 16 row-groups x 128 cols -> 1 atomic/col
        __syncthreads();
        #pragma unroll
        for (int k = 0; k < 8; ++k) colred[lr * 128 + lc0 + k] = cp[k];
        __syncthreads();
        if (tid < 128) {
            float s = 0.f;
            #pragma unroll
            for (int r = 0; r < 16; ++r) s += colred[r * 128 + tid];
            atomicAdd(&csum[bz * 512 + cb0 + tid], s);
        }
    }
}

// ---------- v1 = 1.5*c0/tr - 0.5*c1 ----------
__global__ __launch_bounds__(512) void vkernA(const float* __restrict__ c0,
        const float* __restrict__ c1, const float* __restrict__ tr, float* __restrict__ v) {
    int b = blockIdx.x, c = threadIdx.x;
    float invt = 1.0f / tr[b];
    v[b * 512 + c] = 1.5f * c0[b * 512 + c] * invt - 0.5f * c1[b * 512 + c];
}

// ---------- v = 1.5*v - 0.5*vacc ----------
__global__ __launch_bounds__(512) void vkernB(const float* __restrict__ vacc, float* __restrict__ v) {
    int i = blockIdx.x * 512 + threadIdx.x;
    v[i] = 1.5f * v[i] - 0.5f * vacc[i];
}

// ---------- GEMV: out[b,:] (+)= w[b,:] @ M[b,:,:], M = bf16 hi+lo planes ----------
__global__ __launch_bounds__(512) void gemv_ml(
        const unsigned short* __restrict__ Mh, const unsigned short* __restrict__ Ml,
        const float* __restrict__ a0, const float* __restrict__ a1,
        const float* __restrict__ a2, const float* __restrict__ a3,
        float k0, float k1, float k2, float k3,
        float* __restrict__ wstore, float* __restrict__ out) {
    __shared__ float w[512];
    __shared__ __align__(16) float red[4][512];
    int b  = blockIdx.x & 31;
    int rc = blockIdx.x >> 5;                  // 0..15
    int t  = threadIdx.x;
    float wv = k0 * a0[b * 512 + t];
    if (a1) wv += k1 * a1[b * 512 + t];
    if (a2) wv += k2 * a2[b * 512 + t];
    if (a3) wv += k3 * a3[b * 512 + t];
    w[t] = wv;
    if (wstore != nullptr && rc == 0) wstore[b * 512 + t] = wv;
    __syncthreads();
    int rg = t >> 7, ct = t & 127;             // 4 row-groups x 128 col-threads (4 cols each)
    int row0 = rc * 32 + rg * 8;
    const unsigned short* ph = Mh + ((size_t)b * 512 + row0) * 512 + ct * 4;
    const unsigned short* pl = Ml + ((size_t)b * 512 + row0) * 512 + ct * 4;
    float4 acc = {0.f, 0.f, 0.f, 0.f};
    #pragma unroll
    for (int r = 0; r < 8; ++r) {
        ushort4 h = *(const ushort4*)(ph + (size_t)r * 512);
        ushort4 lo = *(const ushort4*)(pl + (size_t)r * 512);
        float wr = w[row0 + r];
        acc.x += wr * (bf2f(h.x) + bf2f(lo.x));
        acc.y += wr * (bf2f(h.y) + bf2f(lo.y));
        acc.z += wr * (bf2f(h.z) + bf2f(lo.z));
        acc.w += wr * (bf2f(h.w) + bf2f(lo.w));
    }
    *(float4*)&red[rg][ct * 4] = acc;
    __syncthreads();
    float s = red[0][t] + red[1][t] + red[2][t] + red[3][t];
    atomicAdd(&out[b * 512 + t], s);
}

// ---------- out = x * v5[ch]/512*sqrt(tr[b]);  v5 = 1.5v4 -1.125r1 +0.75r2 -0.28125u1 +0.1875u2 -0.03125u3 ----------
__global__ __launch_bounds__(256) void scale_x6(const float* __restrict__ x,
        const float* __restrict__ v4, const float* __restrict__ r1, const float* __restrict__ r2,
        const float* __restrict__ u1, const float* __restrict__ u2, const float* __restrict__ u3,
        const float* __restrict__ tr, float* __restrict__ out) {
    size_t i = (size_t)blockIdx.x * 256 + threadIdx.x;
    size_t ch = i / 196;
    int b = (int)(ch >> 9);
    float v5 = 1.5f * v4[ch] - 1.125f * r1[ch] + 0.75f * r2[ch]
             - 0.28125f * u1[ch] + 0.1875f * u2[ch] - 0.03125f * u3[ch];
    float sc = v5 * (1.0f / 512.0f) * sqrtf(tr[b]);
    float4 vv = ((const float4*)x)[i];
    vv.x *= sc; vv.y *= sc; vv.z *= sc; vv.w *= sc;
    ((float4*)out)[i] = vv;
}

extern "C" void kernel_launch(void* const* d_in, const int* in_sizes, int n_in,
                              void* d_out, int out_size, void* d_ws, size_t ws_size,
                              hipStream_t stream) {
    const float* x = (const float*)d_in[0];
    float* out = (float*)d_out;
    char* ws = (char*)d_ws;

    const size_t PLANE  = (size_t)32 * 512 * 512 * 2;   // 16.78 MB bf16 plane
    const size_t XPLANE = (size_t)32 * 512 * 800 * 2;   // 26.21 MB padded Xc plane
    const size_t SMALL  = (size_t)(2 << 20);            // small-vector region

    float* tr = (float*)ws;                              // 32 f (atomic)
    #define VEC(i) ((float*)(ws + 4096 + (size_t)(i) * 65536))
    float* c0    = VEC(0);  float* c1    = VEC(1);
    float* vacc0 = VEC(2);  float* vacc1 = VEC(3);
    float* v     = VEC(4);                               // evolving v1,v2
    float* v3    = VEC(5);  float* v4    = VEC(6);
    float* r1    = VEC(7);  float* r2    = VEC(8);
    float* p1    = VEC(9);  float* p2    = VEC(10); float* p3 = VEC(11);
    float* q1    = VEC(12); float* q2    = VEC(13); float* q3 = VEC(14);
    float* s1    = VEC(15); float* s2    = VEC(16); float* s3 = VEC(17);
    float* u1    = VEC(18); float* u2    = VEC(19); float* u3 = VEC(20);

    char* big = ws + SMALL;
    unsigned short* Ah = (unsigned short*)(big);                 // cov/M ping
    unsigned short* Al = (unsigned short*)(big + PLANE);
    char* R0 = big + 2 * PLANE;
    unsigned short* Xh = (unsigned short*)(R0);                  // dead after cov
    unsigned short* Xl = (unsigned short*)(R0 + XPLANE);
    unsigned short* Sh = (unsigned short*)(R0);                  // S = M^2 (overlaps X)
    unsigned short* Sl = (unsigned short*)(R0 + PLANE);
    size_t need = SMALL + 2 * PLANE + 2 * XPLANE + 2 * PLANE;
    unsigned short *Bh, *Bl;                                      // M pong
    if (ws_size >= need) {
        Bh = (unsigned short*)(R0 + 2 * XPLANE);
        Bl = (unsigned short*)(R0 + 2 * XPLANE + PLANE);
    } else {                                              // d_out scratch (51.4 MB >= 33.5 MB)
        Bh = (unsigned short*)out;
        Bl = (unsigned short*)out + (size_t)32 * 512 * 512;
    }

    hipMemsetAsync(ws, 0, 4096 + 21 * 65536, stream);    // zero tr + all vector slots (atomics)

    // 1) center + split
    center_convert<<<32 * 512, 256, 0, stream>>>(x, Xh, Xl);
    // 2) cov = Xc@Xc^T/784; fused trace + colsum(cov)->c0
    gemm_sym<3, 1, 0><<<640, 256, 0, stream>>>(Xh, Xl, Xh, Xl, nullptr, nullptr, nullptr, nullptr,
                                               Ah, Al, tr, c0, nullptr, 800, 800, 1.0f / 784.0f);
    // 3) S0 = cov^2/tr^2 ; fused colsum(S0)->c1
    gemm_sym<0, 1, 1><<<640, 256, 0, stream>>>(Ah, Al, Ah, Al, nullptr, nullptr, nullptr, nullptr,
                                               Sh, Sl, tr, c1, nullptr, 512, 512, 1.0f);
    // 4) v1 = 1.5*c0/tr - 0.5*c1
    vkernA<<<32, 512, 0, stream>>>(c0, c1, tr, v);
    // 5) M1 = 0.25(9*cov/tr - 6*S0 + cov@S0/tr) -> B ; fused vacc0 = v1 @ M1
    gemm_sym<1, 2, 1><<<640, 256, 0, stream>>>(Ah, Al, Sh, Sl, Ah, Al, Sh, Sl,
                                               Bh, Bl, tr, vacc0, v, 512, 512, 1.0f);
    // 6) v2 = 1.5*v1 - 0.5*vacc0
    vkernB<<<32, 512, 0, stream>>>(vacc0, v);
    // 7) S1 = M1^2
    gemm_sym<0, 0, 0><<<640, 256, 0, stream>>>(Bh, Bl, Bh, Bl, nullptr, nullptr, nullptr, nullptr,
                                               Sh, Sl, tr, nullptr, nullptr, 512, 512, 1.0f);
    // 8) M2 = 0.25(9*M1 - 6*S1 + M1@S1) -> A ; fused vacc1 = v2 @ M2
    gemm_sym<1, 2, 0><<<640, 256, 0, stream>>>(Bh, Bl, Sh, Sl, Bh, Bl, Sh, Sl,
                                               Ah, Al, tr, vacc1, v, 512, 512, 1.0f);

    // 9) GEMV tail against M2 (Ah/Al): M3 = g(M2), M4 = g(M3) never materialized.
    //    g(x) = 0.25(9x - 6x^2 + x^3); x@g(M) = 2.25(xM) - 1.5(xM^2) + 0.25(xM^3).
    gemv_ml<<<512, 512, 0, stream>>>(Ah, Al, v,  vacc1, nullptr, nullptr, 1.5f, -0.5f, 0.f, 0.f, v3, p1);
    gemv_ml<<<512, 512, 0, stream>>>(Ah, Al, p1, nullptr, nullptr, nullptr, 1.f, 0.f, 0.f, 0.f, nullptr, p2);
    gemv_ml<<<512, 512, 0, stream>>>(Ah, Al, p2, nullptr, nullptr, nullptr, 1.f, 0.f, 0.f, 0.f, nullptr, p3);
    // v4 = 1.5*v3 - 0.5*(v3@M3) = 1.5v3 -1.125p1 +0.75p2 -0.125p3 ; q-chain: q_k = v4 @ M2^k
    gemv_ml<<<512, 512, 0, stream>>>(Ah, Al, v3, p1, p2, p3, 1.5f, -1.125f, 0.75f, -0.125f, v4, q1);
    gemv_ml<<<512, 512, 0, stream>>>(Ah, Al, q1, nullptr, nullptr, nullptr, 1.f, 0.f, 0.f, 0.f, nullptr, q2);
    gemv_ml<<<512, 512, 0, stream>>>(Ah, Al, q2, nullptr, nullptr, nullptr, 1.f, 0.f, 0.f, 0.f, nullptr, q3);
    // r1 = v4@M3 = 2.25q1 -1.5q2 +0.25q3 ; s-chain: s_k = r1 @ M2^k
    gemv_ml<<<512, 512, 0, stream>>>(Ah, Al, q1, q2, q3, nullptr, 2.25f, -1.5f, 0.25f, 0.f, r1, s1);
    gemv_ml<<<512, 512, 0, stream>>>(Ah, Al, s1, nullptr, nullptr, nullptr, 1.f, 0.f, 0.f, 0.f, nullptr, s2);
    gemv_ml<<<512, 512, 0, stream>>>(Ah, Al, s2, nullptr, nullptr, nullptr, 1.f, 0.f, 0.f, 0.f, nullptr, s3);
    // r2 = v4@M3^2 = r1@M3 = 2.25s1 -1.5s2 +0.25s3 ; u-chain: u_k = r2 @ M2^k
    gemv_ml<<<512, 512, 0, stream>>>(Ah, Al, s1, s2, s3, nullptr, 2.25f, -1.5f, 0.25f, 0.f, r2, u1);
    gemv_ml<<<512, 512, 0, stream>>>(Ah, Al, u1, nullptr, nullptr, nullptr, 1.f, 0.f, 0.f, 0.f, nullptr, u2);
    gemv_ml<<<512, 512, 0, stream>>>(Ah, Al, u2, nullptr, nullptr, nullptr, 1.f, 0.f, 0.f, 0.f, nullptr, u3);

    // 10) out = x * v5/512 * sqrt(tr); v5 combine fused (r3 = 2.25u1 -1.5u2 +0.25u3)
    scale_x6<<<12544, 256, 0, stream>>>(x, v4, r1, r2, u1, u2, u3, tr, out);
    #undef VEC
}